// Round 2
// baseline (681.171 us; speedup 1.0000x reference)
//
#include <hip/hip_runtime.h>
#include <hip/hip_bf16.h>
#include <cstddef>

#define Bb 4
#define Mm 2048
#define Dd 1024
#define Nn 64
#define Pp 32
#define NP 2048
#define BM 8192

typedef __attribute__((ext_vector_type(4))) float v4f;
typedef __attribute__((ext_vector_type(8))) short v8s;

__device__ inline unsigned short f2b(float f) {
  union { float f; unsigned u; } v; v.f = f;
  unsigned r = v.u + 0x7fff + ((v.u >> 16) & 1);
  return (unsigned short)(r >> 16);
}

__device__ inline void gld16(const void* g, void* l) {
  __builtin_amdgcn_global_load_lds(
      (const __attribute__((address_space(1))) unsigned*)g,
      (__attribute__((address_space(3))) unsigned*)l, 16, 0, 0);
}

// ---------------------------------------------------------------------------
// k_xprep: one pass over x. Writes xb (bf16, [b][m][d]) and xT (bf16, [b][d][m]).
// ---------------------------------------------------------------------------
__global__ __launch_bounds__(256) void k_xprep(const float* __restrict__ x,
                                               unsigned short* __restrict__ xb,
                                               unsigned short* __restrict__ xT) {
  __shared__ unsigned short t[32][33];
  const int b = blockIdx.z;
  const int r0 = blockIdx.y * 32;   // m
  const int c0 = blockIdx.x * 32;   // d
  const float* ib = x + (size_t)b * Mm * Dd;
  const int tr = threadIdx.x >> 3;
  const int tc = (threadIdx.x & 7) * 4;
  float4 v = *(const float4*)&ib[(size_t)(r0 + tr) * Dd + c0 + tc];
  ushort4 s;
  s.x = f2b(v.x); s.y = f2b(v.y); s.z = f2b(v.z); s.w = f2b(v.w);
  *(ushort4*)&xb[(size_t)b * Mm * Dd + (size_t)(r0 + tr) * Dd + c0 + tc] = s;
  t[tr][tc + 0] = s.x; t[tr][tc + 1] = s.y;
  t[tr][tc + 2] = s.z; t[tr][tc + 3] = s.w;
  __syncthreads();
  ushort4 o;
  o.x = t[tc + 0][tr]; o.y = t[tc + 1][tr];
  o.z = t[tc + 2][tr]; o.w = t[tc + 3][tr];
  *(ushort4*)&xT[(size_t)b * Dd * Mm + (size_t)(c0 + tr) * Mm + r0 + tc] = o;
}

// ---------------------------------------------------------------------------
// tiled transpose fp32 -> bf16 : in [R][C] -> out [C][R] (for phi)
// ---------------------------------------------------------------------------
__global__ __launch_bounds__(256) void k_tr_f2b(const float* __restrict__ in,
                                                unsigned short* __restrict__ out,
                                                int R, int C) {
  __shared__ unsigned short t[32][33];
  const int r0 = blockIdx.y * 32, c0 = blockIdx.x * 32;
  const int tr = threadIdx.x >> 3;
  const int tc = (threadIdx.x & 7) * 4;
  float4 v = *(const float4*)&in[(size_t)(r0 + tr) * C + c0 + tc];
  t[tr][tc + 0] = f2b(v.x); t[tr][tc + 1] = f2b(v.y);
  t[tr][tc + 2] = f2b(v.z); t[tr][tc + 3] = f2b(v.w);
  __syncthreads();
  ushort4 o;
  o.x = t[tc + 0][tr]; o.y = t[tc + 1][tr];
  o.z = t[tc + 2][tr]; o.w = t[tc + 3][tr];
  *(ushort4*)&out[(size_t)(c0 + tr) * R + r0 + tc] = o;
}

// bf16 -> bf16 batched transpose
__global__ __launch_bounds__(256) void k_tr_b2b(const unsigned short* __restrict__ in, size_t sin_,
                                                unsigned short* __restrict__ out, size_t sout,
                                                int R, int C) {
  __shared__ unsigned short t[32][33];
  const int r0 = blockIdx.y * 32, c0 = blockIdx.x * 32;
  const unsigned short* ib = in + (size_t)blockIdx.z * sin_;
  unsigned short* ob = out + (size_t)blockIdx.z * sout;
  const int tr = threadIdx.x >> 3;
  const int tc = (threadIdx.x & 7) * 4;
  ushort4 v = *(const ushort4*)&ib[(size_t)(r0 + tr) * C + c0 + tc];
  t[tr][tc + 0] = v.x; t[tr][tc + 1] = v.y;
  t[tr][tc + 2] = v.z; t[tr][tc + 3] = v.w;
  __syncthreads();
  ushort4 o;
  o.x = t[tc + 0][tr]; o.y = t[tc + 1][tr];
  o.z = t[tc + 2][tr]; o.w = t[tc + 3][tr];
  *(ushort4*)&ob[(size_t)(c0 + tr) * R + r0 + tc] = o;
}

// ---------------------------------------------------------------------------
// k_gemm8: 256x256 tile, BK=32, 4-deep ring of LDS K-tile buffers,
// counted-vmcnt pipeline (T3+T4). C[M,N] = A[M,K] @ B^T[N,K].
// 512 threads = 8 waves (2M x 4N), per-wave output 128x64.
// Per K-tile: issue 4 gld16 for tile t+3, 12 ds_read_b128, 32 MFMA,
// s_waitcnt vmcnt(8) (NEVER 0 in main loop), one s_barrier.
// LDS rows are 64 B (BK=32) -> fr/fc fragment reads give full 1KB coverage
// per wave per ds_read_b128 = conflict-free without swizzle (m97 layout),
// so global_load_lds stays linear (rule 21 satisfied trivially).
// Epilogue peels 3 tiles with vmcnt 8 -> 4 -> 0 (T4 drain formula).
// ---------------------------------------------------------------------------
template <int OUT_BF16>
__global__ __launch_bounds__(512, 2) void k_gemm8(const unsigned short* __restrict__ A, size_t sA,
                                                  const unsigned short* __restrict__ B, size_t sB,
                                                  void* __restrict__ C, size_t sC,
                                                  int M, int N, int K, int nbx) {
  __shared__ unsigned short As[4][256][32];
  __shared__ unsigned short Bs[4][256][32];
  // bijective XCD swizzle (all launches have gridDim.x % 8 == 0)
  const int nwg = (int)gridDim.x;
  const int bid = (int)blockIdx.x;
  const int swz = (bid & 7) * (nwg >> 3) + (bid >> 3);
  const int bx = swz % nbx, by = swz / nbx;
  const int tid = threadIdx.x;
  const int wv = tid >> 6, ln = tid & 63;
  const int wm = wv >> 2, wn = wv & 3;
  const int row0 = by * 256, col0 = bx * 256;
  const unsigned short* Ab = A + (size_t)blockIdx.z * sA + (size_t)row0 * K;
  const unsigned short* Bbp = B + (size_t)blockIdx.z * sB + (size_t)col0 * K;
  const int srow = wv * 32 + (ln >> 2);   // staging row within 256 (wave covers 32 rows)
  const int ssc = (ln & 3) * 8;           // staging k-offset (elements)
  const int fr = ln & 15, fc = (ln >> 4) * 8;
  const int nt = K >> 5;                  // K-tiles of 32
  v4f acc[8][4];
#pragma unroll
  for (int i = 0; i < 8; ++i)
#pragma unroll
    for (int j = 0; j < 4; ++j) { v4f z = {0.f, 0.f, 0.f, 0.f}; acc[i][j] = z; }

#define STAGE8(t, buf) do {                                        \
    size_t ga1 = (size_t)srow * K + (size_t)(t) * 32 + ssc;        \
    size_t ga2 = ga1 + (size_t)16 * K;                             \
    gld16(Ab + ga1,  &As[buf][wv * 32][0]);                        \
    gld16(Ab + ga2,  &As[buf][wv * 32 + 16][0]);                   \
    gld16(Bbp + ga1, &Bs[buf][wv * 32][0]);                        \
    gld16(Bbp + ga2, &Bs[buf][wv * 32 + 16][0]);                   \
  } while (0)

#define COMP8(buf) do {                                            \
    v8s a[8], b[4];                                                \
    _Pragma("unroll")                                              \
    for (int i = 0; i < 8; ++i)                                    \
      a[i] = *(const v8s*)&As[buf][wm * 128 + 16 * i + fr][fc];    \
    _Pragma("unroll")                                              \
    for (int j = 0; j < 4; ++j)                                    \
      b[j] = *(const v8s*)&Bs[buf][wn * 64 + 16 * j + fr][fc];     \
    __builtin_amdgcn_s_setprio(1);                                 \
    _Pragma("unroll")                                              \
    for (int i = 0; i < 8; ++i)                                    \
      _Pragma("unroll")                                            \
      for (int j = 0; j < 4; ++j)                                  \
        acc[i][j] = __builtin_amdgcn_mfma_f32_16x16x32_bf16(a[i], b[j], acc[i][j], 0, 0, 0); \
    __builtin_amdgcn_s_setprio(0);                                 \
  } while (0)

  // prologue: tiles 0..2 in flight (12 loads/thread)
  STAGE8(0, 0);
  STAGE8(1, 1);
  STAGE8(2, 2);
  asm volatile("s_waitcnt vmcnt(8)" ::: "memory");   // tile 0 landed
  __builtin_amdgcn_s_barrier();
  __builtin_amdgcn_sched_barrier(0);

  for (int t = 0; t < nt - 3; ++t) {
    STAGE8(t + 3, (t + 3) & 3);        // into buf last read at tile t-1 (barrier-separated)
    COMP8(t & 3);
    asm volatile("s_waitcnt vmcnt(8)" ::: "memory"); // oldest 4 (tile t+1) landed; t+2,t+3 in flight
    __builtin_amdgcn_s_barrier();
    __builtin_amdgcn_sched_barrier(0);
  }
  // epilogue: drain 8 -> 4 -> 0
  COMP8((nt - 3) & 3);
  asm volatile("s_waitcnt vmcnt(4)" ::: "memory");
  __builtin_amdgcn_s_barrier();
  __builtin_amdgcn_sched_barrier(0);
  COMP8((nt - 2) & 3);
  asm volatile("s_waitcnt vmcnt(0)" ::: "memory");
  __builtin_amdgcn_s_barrier();
  __builtin_amdgcn_sched_barrier(0);
  COMP8((nt - 1) & 3);
#undef STAGE8
#undef COMP8

  const int er = (ln >> 4) * 4, ec = ln & 15;
#pragma unroll
  for (int i = 0; i < 8; ++i)
#pragma unroll
    for (int j = 0; j < 4; ++j) {
      int r = row0 + wm * 128 + 16 * i + er;
      int c = col0 + wn * 64 + 16 * j + ec;
      if (OUT_BF16) {
        unsigned short* Cp = (unsigned short*)C + (size_t)blockIdx.z * sC + (size_t)r * N + c;
#pragma unroll
        for (int q = 0; q < 4; ++q) Cp[(size_t)q * N] = f2b(acc[i][j][q]);
      } else {
        float* Cp = (float*)C + (size_t)blockIdx.z * sC + (size_t)r * N + c;
#pragma unroll
        for (int q = 0; q < 4; ++q) Cp[(size_t)q * N] = acc[i][j][q];
      }
    }
}

// ---------------------------------------------------------------------------
// softmaxes (shuffle-reduce). One block per m.
// ---------------------------------------------------------------------------
__global__ __launch_bounds__(256) void k_softmax(const float* __restrict__ logits,
                                                 unsigned short* __restrict__ dispatch,
                                                 unsigned short* __restrict__ combine) {
  __shared__ float sh[Bb][NP];
  __shared__ float redm[Bb][4];
  __shared__ float reds[Bb][4];
  const int m = blockIdx.x;
  const int tid = threadIdx.x;
  const int wv = tid >> 6, ln = tid & 63;
#pragma unroll
  for (int b = 0; b < Bb; ++b) {
    const float4* src = (const float4*)(logits + ((size_t)b * Mm + m) * NP);
#pragma unroll
    for (int it = 0; it < 2; ++it) ((float4*)sh[b])[tid + it * 256] = src[tid + it * 256];
  }
  __syncthreads();
#pragma unroll
  for (int it = 0; it < 8; ++it) {
    int np = tid + it * 256;
    float v0 = sh[0][np], v1 = sh[1][np], v2 = sh[2][np], v3 = sh[3][np];
    float mx = fmaxf(fmaxf(v0, v1), fmaxf(v2, v3));
    float e0 = __expf(v0 - mx), e1 = __expf(v1 - mx);
    float e2 = __expf(v2 - mx), e3 = __expf(v3 - mx);
    float inv = 1.0f / (e0 + e1 + e2 + e3);
    dispatch[((size_t)0 * Mm + m) * NP + np] = f2b(e0 * inv);
    dispatch[((size_t)1 * Mm + m) * NP + np] = f2b(e1 * inv);
    dispatch[((size_t)2 * Mm + m) * NP + np] = f2b(e2 * inv);
    dispatch[((size_t)3 * Mm + m) * NP + np] = f2b(e3 * inv);
  }
#pragma unroll
  for (int b = 0; b < Bb; ++b) {
    float lmax = -3.0e38f;
#pragma unroll
    for (int it = 0; it < 8; ++it) lmax = fmaxf(lmax, sh[b][tid + it * 256]);
#pragma unroll
    for (int o = 32; o > 0; o >>= 1) lmax = fmaxf(lmax, __shfl_xor(lmax, o, 64));
    if (ln == 0) redm[b][wv] = lmax;
    __syncthreads();
    float mx = fmaxf(fmaxf(redm[b][0], redm[b][1]), fmaxf(redm[b][2], redm[b][3]));
    float lsum = 0.0f;
#pragma unroll
    for (int it = 0; it < 8; ++it) {
      int np = tid + it * 256;
      float e = __expf(sh[b][np] - mx);
      sh[b][np] = e;              // cache: each thread overwrites only its own slots
      lsum += e;
    }
#pragma unroll
    for (int o = 32; o > 0; o >>= 1) lsum += __shfl_xor(lsum, o, 64);
    if (ln == 0) reds[b][wv] = lsum;
    __syncthreads();
    float inv = 1.0f / (reds[b][0] + reds[b][1] + reds[b][2] + reds[b][3]);
#pragma unroll
    for (int it = 0; it < 8; ++it) {
      int np = tid + it * 256;
      combine[((size_t)b * Mm + m) * NP + np] = f2b(sh[b][np] * inv);
    }
  }
}

// ---------------------------------------------------------------------------
// k_y: per expert n, BK=64 dual-buffer. A (slots) via gld16; W fp32 staged
// through VALU cvt into padded LDS. HBM-bound on the 268 MB W read.
// ---------------------------------------------------------------------------
__global__ __launch_bounds__(256) void k_y_mfma(const unsigned short* __restrict__ slots,
                                                const float* __restrict__ W,
                                                const float* __restrict__ bias,
                                                unsigned short* __restrict__ y) {
  __shared__ unsigned short As[2][128][32];
  __shared__ unsigned short Bs[2][128][40];
  const int n = blockIdx.z;
  const int col0 = blockIdx.x * 128;
  const int tid = threadIdx.x;
  const int wv = tid >> 6, ln = tid & 63;
  const int wm = wv & 1, wn = wv >> 1;
  const int sr = ln >> 2, sc = (ln & 3) * 8;
  const int fr = ln & 15, fc = (ln >> 4) * 8;
  const float* Wn = W + (size_t)n * Dd * Dd;
  v4f acc[4][4];
#pragma unroll
  for (int i = 0; i < 4; ++i)
#pragma unroll
    for (int j = 0; j < 4; ++j) { v4f z = {0.f, 0.f, 0.f, 0.f}; acc[i][j] = z; }

  for (int kt = 0; kt < Dd; kt += 64) {
    __syncthreads();
    {
      int r1 = 32 * wv + sr;
      int r2 = r1 + 16;
      size_t g1 = ((size_t)(r1 >> 5) * NP + n * Pp + (r1 & 31)) * Dd + kt + sc;
      size_t g2 = ((size_t)(r2 >> 5) * NP + n * Pp + (r2 & 31)) * Dd + kt + sc;
      gld16(slots + g1,      &As[0][32 * wv][0]);
      gld16(slots + g2,      &As[0][32 * wv + 16][0]);
      gld16(slots + g1 + 32, &As[1][32 * wv][0]);
      gld16(slots + g2 + 32, &As[1][32 * wv + 16][0]);
    }
#pragma unroll
    for (int buf = 0; buf < 2; ++buf) {
#pragma unroll
      for (int it = 0; it < 2; ++it) {
        int idx = tid + it * 256;
        int k = ((idx >> 2) & 15) * 2;                    // 16 k-pairs per wave
        int eseg = ((idx & 3) + ((idx >> 6) << 2)) * 4;   // 4-lane e-groups (64B lines)
        const float* wp = &Wn[(size_t)(kt + buf * 32 + k) * Dd + col0 + eseg];
        float4 r0 = *(const float4*)wp;
        float4 r1 = *(const float4*)(wp + Dd);
        *(__hip_bfloat162*)&Bs[buf][eseg + 0][k] = __float22bfloat162_rn(float2{r0.x, r1.x});
        *(__hip_bfloat162*)&Bs[buf][eseg + 1][k] = __float22bfloat162_rn(float2{r0.y, r1.y});
        *(__hip_bfloat162*)&Bs[buf][eseg + 2][k] = __float22bfloat162_rn(float2{r0.z, r1.z});
        *(__hip_bfloat162*)&Bs[buf][eseg + 3][k] = __float22bfloat162_rn(float2{r0.w, r1.w});
      }
    }
    __syncthreads();
#pragma unroll
    for (int ks = 0; ks < 2; ++ks) {
      v8s a[4], b[4];
#pragma unroll
      for (int i = 0; i < 4; ++i) a[i] = *(const v8s*)&As[ks][64 * wm + 16 * i + fr][fc];
#pragma unroll
      for (int j = 0; j < 4; ++j) b[j] = *(const v8s*)&Bs[ks][64 * wn + 16 * j + fr][fc];
#pragma unroll
      for (int i = 0; i < 4; ++i)
#pragma unroll
        for (int j = 0; j < 4; ++j)
          acc[i][j] = __builtin_amdgcn_mfma_f32_16x16x32_bf16(a[i], b[j], acc[i][j], 0, 0, 0);
    }
  }
  const int er = (ln >> 4) * 4, ec = ln & 15;
  float bv[4];
#pragma unroll
  for (int j = 0; j < 4; ++j) bv[j] = bias[(size_t)n * Dd + col0 + 64 * wn + 16 * j + ec];
#pragma unroll
  for (int i = 0; i < 4; ++i)
#pragma unroll
    for (int j = 0; j < 4; ++j) {
      int c = col0 + 64 * wn + 16 * j + ec;
#pragma unroll
      for (int q = 0; q < 4; ++q) {
        int r = 64 * wm + 16 * i + er + q;
        size_t row = (size_t)(r >> 5) * NP + n * Pp + (r & 31);
        y[row * Dd + c] = f2b(acc[i][j][q] + bv[j]);
      }
    }
}

// ---------------------------------------------------------------------------
extern "C" void kernel_launch(void* const* d_in, const int* in_sizes, int n_in,
                              void* d_out, int out_size, void* d_ws, size_t ws_size,
                              hipStream_t stream) {
  const float* x    = (const float*)d_in[0];
  const float* phi  = (const float*)d_in[1];
  const float* W    = (const float*)d_in[2];
  const float* bias = (const float*)d_in[3];
  float* out = (float*)d_out;
  char* ws = (char*)d_ws;

  float*          logits = (float*)(ws);                            // 67.1 MB
  unsigned short* disp_b = (unsigned short*)(ws + 67108864);        // 33.5 MB
  unsigned short* comb_b = (unsigned short*)(ws + 100663296);       // 33.5 MB
  unsigned short* dispT  = (unsigned short*)(ws + 134217728);       // 33.5 MB
  unsigned short* xb     = (unsigned short*)(ws + 167772160);       // 16.8 MB
  unsigned short* xT     = (unsigned short*)(ws + 184549376);       // 16.8 MB
  unsigned short* phiT   = (unsigned short*)(ws + 201326592);       //  4.2 MB
  unsigned short* slots  = (unsigned short*)(ws + 209715200);       // 16.8 MB
  unsigned short* y_b    = (unsigned short*)(ws + 226492416);       // 16.8 MB
  unsigned short* yT     = (unsigned short*)(ws + 243269632);       // 16.8 MB

  k_xprep<<<dim3(32, 64, Bb), 256, 0, stream>>>(x, xb, xT);
  k_tr_f2b<<<dim3(64, 32, 1), 256, 0, stream>>>(phi, phiT, Dd, NP);
  // logits = xb @ phiT^T : M=8192, N=2048, K=1024 -> 32x8 = 256 blocks (1/CU)
  k_gemm8<0><<<dim3(256, 1, 1), 512, 0, stream>>>(xb, 0, phiT, 0, logits, 0, BM, NP, Dd, 8);
  k_softmax<<<Mm, 256, 0, stream>>>(logits, disp_b, comb_b);
  k_tr_b2b<<<dim3(64, 64, Bb), 256, 0, stream>>>(disp_b, (size_t)Mm * NP, dispT, (size_t)NP * Mm, Mm, NP);
  // slots = dispT @ xT^T per b : M=2048, N=1024, K=2048 -> 8x4 = 32 blocks x 4
  k_gemm8<1><<<dim3(32, 1, Bb), 512, 0, stream>>>(dispT, (size_t)NP * Mm, xT, (size_t)Dd * Mm,
                                                  slots, (size_t)NP * Dd, NP, Dd, Mm, 4);
  k_y_mfma<<<dim3(8, 1, Nn), 256, 0, stream>>>(slots, W, bias, y_b);
  k_tr_b2b<<<dim3(32, 64, Bb), 256, 0, stream>>>(y_b, (size_t)NP * Dd, yT, (size_t)Dd * NP, NP, Dd);
  // out = comb_b @ yT^T per b : M=2048, N=1024, K=2048
  k_gemm8<0><<<dim3(32, 1, Bb), 512, 0, stream>>>(comb_b, (size_t)Mm * NP, yT, (size_t)Dd * NP,
                                                  out, (size_t)Mm * Dd, Mm, Dd, NP, 4);
}

// Round 3
// 657.700 us; speedup vs baseline: 1.0357x; 1.0357x over previous
//
#include <hip/hip_runtime.h>
#include <hip/hip_bf16.h>
#include <cstddef>

#define Bb 4
#define Mm 2048
#define Dd 1024
#define Nn 64
#define Pp 32
#define NP 2048
#define BM 8192

typedef __attribute__((ext_vector_type(4))) float v4f;
typedef __attribute__((ext_vector_type(8))) short v8s;

__device__ inline unsigned short f2b(float f) {
  union { float f; unsigned u; } v; v.f = f;
  unsigned r = v.u + 0x7fff + ((v.u >> 16) & 1);
  return (unsigned short)(r >> 16);
}

__device__ inline void gld16(const void* g, void* l) {
  __builtin_amdgcn_global_load_lds(
      (const __attribute__((address_space(1))) unsigned*)g,
      (__attribute__((address_space(3))) unsigned*)l, 16, 0, 0);
}

// ---------------------------------------------------------------------------
// k_xprep: one pass over x. Writes xb (bf16, [b][m][d]) and xT (bf16, [b][d][m]).
// ---------------------------------------------------------------------------
__global__ __launch_bounds__(256) void k_xprep(const float* __restrict__ x,
                                               unsigned short* __restrict__ xb,
                                               unsigned short* __restrict__ xT) {
  __shared__ unsigned short t[32][33];
  const int b = blockIdx.z;
  const int r0 = blockIdx.y * 32;   // m
  const int c0 = blockIdx.x * 32;   // d
  const float* ib = x + (size_t)b * Mm * Dd;
  const int tr = threadIdx.x >> 3;
  const int tc = (threadIdx.x & 7) * 4;
  float4 v = *(const float4*)&ib[(size_t)(r0 + tr) * Dd + c0 + tc];
  ushort4 s;
  s.x = f2b(v.x); s.y = f2b(v.y); s.z = f2b(v.z); s.w = f2b(v.w);
  *(ushort4*)&xb[(size_t)b * Mm * Dd + (size_t)(r0 + tr) * Dd + c0 + tc] = s;
  t[tr][tc + 0] = s.x; t[tr][tc + 1] = s.y;
  t[tr][tc + 2] = s.z; t[tr][tc + 3] = s.w;
  __syncthreads();
  ushort4 o;
  o.x = t[tc + 0][tr]; o.y = t[tc + 1][tr];
  o.z = t[tc + 2][tr]; o.w = t[tc + 3][tr];
  *(ushort4*)&xT[(size_t)b * Dd * Mm + (size_t)(c0 + tr) * Mm + r0 + tc] = o;
}

// ---------------------------------------------------------------------------
// tiled transpose fp32 -> bf16 : in [R][C] -> out [C][R] (for phi)
// ---------------------------------------------------------------------------
__global__ __launch_bounds__(256) void k_tr_f2b(const float* __restrict__ in,
                                                unsigned short* __restrict__ out,
                                                int R, int C) {
  __shared__ unsigned short t[32][33];
  const int r0 = blockIdx.y * 32, c0 = blockIdx.x * 32;
  const int tr = threadIdx.x >> 3;
  const int tc = (threadIdx.x & 7) * 4;
  float4 v = *(const float4*)&in[(size_t)(r0 + tr) * C + c0 + tc];
  t[tr][tc + 0] = f2b(v.x); t[tr][tc + 1] = f2b(v.y);
  t[tr][tc + 2] = f2b(v.z); t[tr][tc + 3] = f2b(v.w);
  __syncthreads();
  ushort4 o;
  o.x = t[tc + 0][tr]; o.y = t[tc + 1][tr];
  o.z = t[tc + 2][tr]; o.w = t[tc + 3][tr];
  *(ushort4*)&out[(size_t)(c0 + tr) * R + r0 + tc] = o;
}

// bf16 -> bf16 batched transpose
__global__ __launch_bounds__(256) void k_tr_b2b(const unsigned short* __restrict__ in, size_t sin_,
                                                unsigned short* __restrict__ out, size_t sout,
                                                int R, int C) {
  __shared__ unsigned short t[32][33];
  const int r0 = blockIdx.y * 32, c0 = blockIdx.x * 32;
  const unsigned short* ib = in + (size_t)blockIdx.z * sin_;
  unsigned short* ob = out + (size_t)blockIdx.z * sout;
  const int tr = threadIdx.x >> 3;
  const int tc = (threadIdx.x & 7) * 4;
  ushort4 v = *(const ushort4*)&ib[(size_t)(r0 + tr) * C + c0 + tc];
  t[tr][tc + 0] = v.x; t[tr][tc + 1] = v.y;
  t[tr][tc + 2] = v.z; t[tr][tc + 3] = v.w;
  __syncthreads();
  ushort4 o;
  o.x = t[tc + 0][tr]; o.y = t[tc + 1][tr];
  o.z = t[tc + 2][tr]; o.w = t[tc + 3][tr];
  *(ushort4*)&ob[(size_t)(c0 + tr) * R + r0 + tc] = o;
}

// ---------------------------------------------------------------------------
// k_g8: fine-interleaved pipelined GEMM. C[M,N] = A[M,K] @ B^T[N,K].
// Tile = (MF*32) x 256, BK=32. 512 threads = 8 waves (2M x 4N),
// wave tile = (MF*16) x 64, acc[MF][4].
// 3-deep ring of K-tile LDS buffers; staging issued in tile t lands for
// tile t+2 (loads cross >=4 barriers). Per tile, 2 phases:
//   ph0: issue A-stage(t+2) | read b[0..3], a[0..MF/2) | bar | 16 MFMA | bar
//   ph1: issue B-stage(t+2) | read a[MF/2..MF) | vmcnt(LPT)+bar (iron) | 16 MFMA | bar
// vmcnt is counted (LPT = MF/4+2), never 0 in the main loop (T3+T4).
// Ledger invariant: at tile-t entry only t+1's LPT loads are outstanding;
// the iron at tile t retires exactly t+1's loads and certifies them for all
// waves via the fused s_barrier (asm memory clobber = compiler fence).
// T2 swizzle both-sides (rule 21): linear gld16 dest; SOURCE chunk ^2 when
// dest-row bit3 set; READ column ^16 elems when fr&8. Same involution.
// ---------------------------------------------------------------------------
template <int MF, int OUT_BF16>   // MF = M-frags per wave: 8 -> 256-row tile, 4 -> 128
__global__ __launch_bounds__(512) void k_g8(const unsigned short* __restrict__ A, size_t sA,
                                            const unsigned short* __restrict__ B, size_t sB,
                                            void* __restrict__ C, size_t sC,
                                            int M, int N, int K, int nbx) {
  constexpr int BMt = MF * 32;
  constexpr int LA  = MF / 4;        // A gld16 per thread per tile (2 or 1)
  constexpr int LPT = LA + 2;        // loads per thread per tile (A + B)
  __shared__ unsigned short As[3][BMt][32];
  __shared__ unsigned short Bs[3][256][32];
  const int nwg = (int)gridDim.x;
  const int bid = (int)blockIdx.x;
  const int swz = (bid & 7) * (nwg >> 3) + (bid >> 3);   // bijective: nwg % 8 == 0
  const int bx = swz % nbx, by = swz / nbx;
  const int tid = (int)threadIdx.x;
  const int wv = tid >> 6, ln = tid & 63;
  const int wm = wv >> 2, wn = wv & 3;
  const int row0 = by * BMt, col0 = bx * 256;
  const unsigned short* Ab = A + (size_t)blockIdx.z * sA + (size_t)row0 * K;
  const unsigned short* Bbp = B + (size_t)blockIdx.z * sB + (size_t)col0 * K;
  const int rowg0 = 16 * wv + (ln >> 2);                       // staging row (dest & src)
  const int csrc = (((ln & 3) ^ ((ln & 32) ? 2 : 0)) << 3);    // pre-swizzled src col (elems)
  const int fr = ln & 15;
  const int fce = (((ln >> 4) << 3) ^ ((fr & 8) ? 16 : 0));    // swizzled read col (elems)
  const int nt = K >> 5;
  v4f acc[MF][4];
#pragma unroll
  for (int i = 0; i < MF; ++i)
#pragma unroll
    for (int j = 0; j < 4; ++j) { v4f z = {0.f, 0.f, 0.f, 0.f}; acc[i][j] = z; }

#define STG_A(t_, r_) do {                                                  \
    size_t g0 = (size_t)rowg0 * K + (size_t)(t_) * 32 + csrc;               \
    gld16(Ab + g0, &As[r_][16 * wv][0]);                                    \
    if (LA == 2) gld16(Ab + g0 + (size_t)128 * K, &As[r_][16 * wv + 128][0]); \
  } while (0)
#define STG_B(t_, r_) do {                                                  \
    size_t g0 = (size_t)rowg0 * K + (size_t)(t_) * 32 + csrc;               \
    gld16(Bbp + g0, &Bs[r_][16 * wv][0]);                                   \
    gld16(Bbp + g0 + (size_t)128 * K, &Bs[r_][16 * wv + 128][0]);           \
  } while (0)
#define RD_B(r_) do {                                                       \
    _Pragma("unroll")                                                       \
    for (int j = 0; j < 4; ++j)                                             \
      bfr[j] = *(const v8s*)&Bs[r_][wn * 64 + 16 * j + fr][fce];            \
  } while (0)
#define RD_A(r_, half_) do {                                                \
    _Pragma("unroll")                                                       \
    for (int i = 0; i < MF / 2; ++i)                                        \
      afr[i] = *(const v8s*)&As[r_][wm * (MF * 16) + 16 * ((half_) * (MF / 2) + i) + fr][fce]; \
  } while (0)
#define MMA(half_) do {                                                     \
    __builtin_amdgcn_s_setprio(1);                                          \
    _Pragma("unroll")                                                       \
    for (int i = 0; i < MF / 2; ++i)                                        \
      _Pragma("unroll")                                                     \
      for (int j = 0; j < 4; ++j)                                           \
        acc[(half_) * (MF / 2) + i][j] =                                    \
            __builtin_amdgcn_mfma_f32_16x16x32_bf16(afr[i], bfr[j],         \
                acc[(half_) * (MF / 2) + i][j], 0, 0, 0);                   \
    __builtin_amdgcn_s_setprio(0);                                          \
  } while (0)
#define IRON(n_) asm volatile("s_waitcnt vmcnt(" #n_ ")\n\ts_barrier" ::: "memory")

  // prologue: stage tiles 0 and 1; certify tile 0
  STG_A(0, 0); STG_B(0, 0);
  STG_A(1, 1); STG_B(1, 1);
  if constexpr (LPT == 4) IRON(4); else IRON(3);
  __builtin_amdgcn_sched_barrier(0);

  int rc = 0;
  for (int t = 0; t < nt - 2; ++t) {
    int rn = rc + 2; if (rn >= 3) rn -= 3;
    v8s bfr[4], afr[MF / 2];
    // ---- phase 0 ----
    STG_A(t + 2, rn);
    RD_B(rc);
    RD_A(rc, 0);
    __builtin_amdgcn_s_barrier();
    __builtin_amdgcn_sched_barrier(0);
    MMA(0);
    __builtin_amdgcn_sched_barrier(0);
    __builtin_amdgcn_s_barrier();
    // ---- phase 1 ----
    STG_B(t + 2, rn);
    RD_A(rc, 1);
    if constexpr (LPT == 4) IRON(4); else IRON(3);   // certify tile t+1; t+2 stays in flight
    __builtin_amdgcn_sched_barrier(0);
    MMA(1);
    __builtin_amdgcn_sched_barrier(0);
    __builtin_amdgcn_s_barrier();
    rc = rc + 1; if (rc >= 3) rc -= 3;
  }
  // ---- epilogue tile nt-2 (data certified by last iron) ----
  {
    v8s bfr[4], afr[MF / 2];
    RD_B(rc); RD_A(rc, 0); MMA(0);
    RD_A(rc, 1); MMA(1);
    IRON(0);                                          // certify tile nt-1
    __builtin_amdgcn_sched_barrier(0);
    rc = rc + 1; if (rc >= 3) rc -= 3;
  }
  // ---- epilogue tile nt-1 ----
  {
    v8s bfr[4], afr[MF / 2];
    RD_B(rc); RD_A(rc, 0); MMA(0);
    RD_A(rc, 1); MMA(1);
  }
#undef STG_A
#undef STG_B
#undef RD_B
#undef RD_A
#undef MMA
#undef IRON

  const int er = (ln >> 4) * 4, ec = ln & 15;
#pragma unroll
  for (int i = 0; i < MF; ++i)
#pragma unroll
    for (int j = 0; j < 4; ++j) {
      int r = row0 + wm * (MF * 16) + 16 * i + er;
      int c = col0 + wn * 64 + 16 * j + ec;
      if (OUT_BF16) {
        unsigned short* Cp = (unsigned short*)C + (size_t)blockIdx.z * sC + (size_t)r * N + c;
#pragma unroll
        for (int q = 0; q < 4; ++q) Cp[(size_t)q * N] = f2b(acc[i][j][q]);
      } else {
        float* Cp = (float*)C + (size_t)blockIdx.z * sC + (size_t)r * N + c;
#pragma unroll
        for (int q = 0; q < 4; ++q) Cp[(size_t)q * N] = acc[i][j][q];
      }
    }
}

// ---------------------------------------------------------------------------
// softmaxes (shuffle-reduce). One block per m.
// ---------------------------------------------------------------------------
__global__ __launch_bounds__(256) void k_softmax(const float* __restrict__ logits,
                                                 unsigned short* __restrict__ dispatch,
                                                 unsigned short* __restrict__ combine) {
  __shared__ float sh[Bb][NP];
  __shared__ float redm[Bb][4];
  __shared__ float reds[Bb][4];
  const int m = blockIdx.x;
  const int tid = threadIdx.x;
  const int wv = tid >> 6, ln = tid & 63;
#pragma unroll
  for (int b = 0; b < Bb; ++b) {
    const float4* src = (const float4*)(logits + ((size_t)b * Mm + m) * NP);
#pragma unroll
    for (int it = 0; it < 2; ++it) ((float4*)sh[b])[tid + it * 256] = src[tid + it * 256];
  }
  __syncthreads();
#pragma unroll
  for (int it = 0; it < 8; ++it) {
    int np = tid + it * 256;
    float v0 = sh[0][np], v1 = sh[1][np], v2 = sh[2][np], v3 = sh[3][np];
    float mx = fmaxf(fmaxf(v0, v1), fmaxf(v2, v3));
    float e0 = __expf(v0 - mx), e1 = __expf(v1 - mx);
    float e2 = __expf(v2 - mx), e3 = __expf(v3 - mx);
    float inv = 1.0f / (e0 + e1 + e2 + e3);
    dispatch[((size_t)0 * Mm + m) * NP + np] = f2b(e0 * inv);
    dispatch[((size_t)1 * Mm + m) * NP + np] = f2b(e1 * inv);
    dispatch[((size_t)2 * Mm + m) * NP + np] = f2b(e2 * inv);
    dispatch[((size_t)3 * Mm + m) * NP + np] = f2b(e3 * inv);
  }
#pragma unroll
  for (int b = 0; b < Bb; ++b) {
    float lmax = -3.0e38f;
#pragma unroll
    for (int it = 0; it < 8; ++it) lmax = fmaxf(lmax, sh[b][tid + it * 256]);
#pragma unroll
    for (int o = 32; o > 0; o >>= 1) lmax = fmaxf(lmax, __shfl_xor(lmax, o, 64));
    if (ln == 0) redm[b][wv] = lmax;
    __syncthreads();
    float mx = fmaxf(fmaxf(redm[b][0], redm[b][1]), fmaxf(redm[b][2], redm[b][3]));
    float lsum = 0.0f;
#pragma unroll
    for (int it = 0; it < 8; ++it) {
      int np = tid + it * 256;
      float e = __expf(sh[b][np] - mx);
      sh[b][np] = e;              // cache: each thread overwrites only its own slots
      lsum += e;
    }
#pragma unroll
    for (int o = 32; o > 0; o >>= 1) lsum += __shfl_xor(lsum, o, 64);
    if (ln == 0) reds[b][wv] = lsum;
    __syncthreads();
    float inv = 1.0f / (reds[b][0] + reds[b][1] + reds[b][2] + reds[b][3]);
#pragma unroll
    for (int it = 0; it < 8; ++it) {
      int np = tid + it * 256;
      combine[((size_t)b * Mm + m) * NP + np] = f2b(sh[b][np] * inv);
    }
  }
}

// ---------------------------------------------------------------------------
// k_y: per expert n, BK=64 dual-buffer. A (slots) via gld16; W fp32 staged
// through VALU cvt into padded LDS. HBM-bound on the 268 MB W read.
// ---------------------------------------------------------------------------
__global__ __launch_bounds__(256) void k_y_mfma(const unsigned short* __restrict__ slots,
                                                const float* __restrict__ W,
                                                const float* __restrict__ bias,
                                                unsigned short* __restrict__ y) {
  __shared__ unsigned short As[2][128][32];
  __shared__ unsigned short Bs[2][128][40];
  const int n = blockIdx.z;
  const int col0 = blockIdx.x * 128;
  const int tid = threadIdx.x;
  const int wv = tid >> 6, ln = tid & 63;
  const int wm = wv & 1, wn = wv >> 1;
  const int sr = ln >> 2, sc = (ln & 3) * 8;
  const int fr = ln & 15, fc = (ln >> 4) * 8;
  const float* Wn = W + (size_t)n * Dd * Dd;
  v4f acc[4][4];
#pragma unroll
  for (int i = 0; i < 4; ++i)
#pragma unroll
    for (int j = 0; j < 4; ++j) { v4f z = {0.f, 0.f, 0.f, 0.f}; acc[i][j] = z; }

  for (int kt = 0; kt < Dd; kt += 64) {
    __syncthreads();
    {
      int r1 = 32 * wv + sr;
      int r2 = r1 + 16;
      size_t g1 = ((size_t)(r1 >> 5) * NP + n * Pp + (r1 & 31)) * Dd + kt + sc;
      size_t g2 = ((size_t)(r2 >> 5) * NP + n * Pp + (r2 & 31)) * Dd + kt + sc;
      gld16(slots + g1,      &As[0][32 * wv][0]);
      gld16(slots + g2,      &As[0][32 * wv + 16][0]);
      gld16(slots + g1 + 32, &As[1][32 * wv][0]);
      gld16(slots + g2 + 32, &As[1][32 * wv + 16][0]);
    }
#pragma unroll
    for (int buf = 0; buf < 2; ++buf) {
#pragma unroll
      for (int it = 0; it < 2; ++it) {
        int idx = tid + it * 256;
        int k = ((idx >> 2) & 15) * 2;                    // 16 k-pairs per wave
        int eseg = ((idx & 3) + ((idx >> 6) << 2)) * 4;   // 4-lane e-groups (64B lines)
        const float* wp = &Wn[(size_t)(kt + buf * 32 + k) * Dd + col0 + eseg];
        float4 r0 = *(const float4*)wp;
        float4 r1 = *(const float4*)(wp + Dd);
        *(__hip_bfloat162*)&Bs[buf][eseg + 0][k] = __float22bfloat162_rn(float2{r0.x, r1.x});
        *(__hip_bfloat162*)&Bs[buf][eseg + 1][k] = __float22bfloat162_rn(float2{r0.y, r1.y});
        *(__hip_bfloat162*)&Bs[buf][eseg + 2][k] = __float22bfloat162_rn(float2{r0.z, r1.z});
        *(__hip_bfloat162*)&Bs[buf][eseg + 3][k] = __float22bfloat162_rn(float2{r0.w, r1.w});
      }
    }
    __syncthreads();
#pragma unroll
    for (int ks = 0; ks < 2; ++ks) {
      v8s a[4], b[4];
#pragma unroll
      for (int i = 0; i < 4; ++i) a[i] = *(const v8s*)&As[ks][64 * wm + 16 * i + fr][fc];
#pragma unroll
      for (int j = 0; j < 4; ++j) b[j] = *(const v8s*)&Bs[ks][64 * wn + 16 * j + fr][fc];
#pragma unroll
      for (int i = 0; i < 4; ++i)
#pragma unroll
        for (int j = 0; j < 4; ++j)
          acc[i][j] = __builtin_amdgcn_mfma_f32_16x16x32_bf16(a[i], b[j], acc[i][j], 0, 0, 0);
    }
  }
  const int er = (ln >> 4) * 4, ec = ln & 15;
  float bv[4];
#pragma unroll
  for (int j = 0; j < 4; ++j) bv[j] = bias[(size_t)n * Dd + col0 + 64 * wn + 16 * j + ec];
#pragma unroll
  for (int i = 0; i < 4; ++i)
#pragma unroll
    for (int j = 0; j < 4; ++j) {
      int c = col0 + 64 * wn + 16 * j + ec;
#pragma unroll
      for (int q = 0; q < 4; ++q) {
        int r = 64 * wm + 16 * i + er + q;
        size_t row = (size_t)(r >> 5) * NP + n * Pp + (r & 31);
        y[row * Dd + c] = f2b(acc[i][j][q] + bv[j]);
      }
    }
}

// ---------------------------------------------------------------------------
extern "C" void kernel_launch(void* const* d_in, const int* in_sizes, int n_in,
                              void* d_out, int out_size, void* d_ws, size_t ws_size,
                              hipStream_t stream) {
  const float* x    = (const float*)d_in[0];
  const float* phi  = (const float*)d_in[1];
  const float* W    = (const float*)d_in[2];
  const float* bias = (const float*)d_in[3];
  float* out = (float*)d_out;
  char* ws = (char*)d_ws;

  float*          logits = (float*)(ws);                            // 67.1 MB
  unsigned short* disp_b = (unsigned short*)(ws + 67108864);        // 33.5 MB
  unsigned short* comb_b = (unsigned short*)(ws + 100663296);       // 33.5 MB
  unsigned short* dispT  = (unsigned short*)(ws + 134217728);       // 33.5 MB
  unsigned short* xb     = (unsigned short*)(ws + 167772160);       // 16.8 MB
  unsigned short* xT     = (unsigned short*)(ws + 184549376);       // 16.8 MB
  unsigned short* phiT   = (unsigned short*)(ws + 201326592);       //  4.2 MB
  unsigned short* slots  = (unsigned short*)(ws + 209715200);       // 16.8 MB
  unsigned short* y_b    = (unsigned short*)(ws + 226492416);       // 16.8 MB
  unsigned short* yT     = (unsigned short*)(ws + 243269632);       // 16.8 MB

  k_xprep<<<dim3(32, 64, Bb), 256, 0, stream>>>(x, xb, xT);
  k_tr_f2b<<<dim3(64, 32, 1), 256, 0, stream>>>(phi, phiT, Dd, NP);
  // logits = xb @ phiT^T : M=8192 N=2048 K=1024. 256x256 tiles -> 32x8 = 256 blocks (1/CU).
  k_g8<8, 0><<<dim3(256, 1, 1), 512, 0, stream>>>(xb, 0, phiT, 0, logits, 0, BM, NP, Dd, 8);
  k_softmax<<<Mm, 256, 0, stream>>>(logits, disp_b, comb_b);
  k_tr_b2b<<<dim3(64, 64, Bb), 256, 0, stream>>>(disp_b, (size_t)Mm * NP, dispT, (size_t)NP * Mm, Mm, NP);
  // slots = dispT @ xT^T per b : M=2048 N=1024 K=2048. 128x256 tiles -> 16x4 = 64 blocks x4 = 256.
  k_g8<4, 1><<<dim3(64, 1, Bb), 512, 0, stream>>>(dispT, (size_t)NP * Mm, xT, (size_t)Dd * Mm,
                                                  slots, (size_t)NP * Dd, NP, Dd, Mm, 4);
  k_y_mfma<<<dim3(8, 1, Nn), 256, 0, stream>>>(slots, W, bias, y_b);
  k_tr_b2b<<<dim3(32, 64, Bb), 256, 0, stream>>>(y_b, (size_t)NP * Dd, yT, (size_t)Dd * NP, NP, Dd);
  // out = comb_b @ yT^T per b : M=2048 N=1024 K=2048.
  k_g8<4, 0><<<dim3(64, 1, Bb), 512, 0, stream>>>(comb_b, (size_t)Mm * NP, yT, (size_t)Dd * NP,
                                                  out, (size_t)Mm * Dd, Mm, Dd, NP, 4);
}